// Round 6
// baseline (233.437 us; speedup 1.0000x reference)
//
#include <hip/hip_runtime.h>
#include <hip/hip_bf16.h>
#include <math.h>

#define N_WIRES 12
#define DIM     4096
#define BATCH   128
#define BD      (BATCH*DIM)
#define BM      128
#define BN      32
#define BK      64
#define KS      8
#define KCHUNK  (DIM / KS)   // 512

typedef __attribute__((ext_vector_type(4))) float f32x4;
typedef __attribute__((ext_vector_type(4))) unsigned int u32x4;
typedef __bf16 bf16x8 __attribute__((ext_vector_type(8)));
typedef __attribute__((ext_vector_type(8))) unsigned short us8;
typedef __attribute__((ext_vector_type(4))) unsigned short us4;

__device__ __forceinline__ f32x4 mfma16(bf16x8 a, bf16x8 b, f32x4 c){
  return __builtin_amdgcn_mfma_f32_16x16x32_bf16(a, b, c, 0, 0, 0);
}

__device__ __forceinline__ float bf2f(unsigned short u){
  union { unsigned int i; float f; } cv; cv.i = ((unsigned int)u) << 16; return cv.f;
}

// State layout (bf16): [c][b][DIM], fully linear (no swizzle — X is consumed
// straight from L2 by the GEMM, no LDS staging).

// ---------------------------------------------------------------- normalize
__global__ void k_normalize(const float* __restrict__ x, __hip_bfloat16* __restrict__ dst){
  const int b = blockIdx.x, t = threadIdx.x;
  const float4* xr = reinterpret_cast<const float4*>(x + (size_t)b * DIM);
  float4 v[4];
  float ss = 0.f;
  #pragma unroll
  for (int r = 0; r < 4; ++r){
    v[r] = xr[t*4 + r];
    ss += v[r].x*v[r].x + v[r].y*v[r].y + v[r].z*v[r].z + v[r].w*v[r].w;
  }
  #pragma unroll
  for (int off = 32; off > 0; off >>= 1) ss += __shfl_down(ss, off);
  __shared__ float sred[4];
  if ((t & 63) == 0) sred[t >> 6] = ss;
  __syncthreads();
  const float inv = 1.f / sqrtf(sred[0] + sred[1] + sred[2] + sred[3]);
  #pragma unroll
  for (int h = 0; h < 2; ++h){
    union { __bf16 e[8]; us8 s; } pk;
    const float* vv = reinterpret_cast<const float*>(&v[h*2]);
    #pragma unroll
    for (int j = 0; j < 8; ++j) pk.e[j] = (__bf16)(vv[j] * inv);
    *reinterpret_cast<us8*>(dst + (size_t)b*DIM + t*16 + h*8) = pk.s;
  }
}

// ---------------------------------------------------------------- complex GEMM
// C[b,n] = sum_k U[n,k] * X[b,k], K split into KS partials (bf16 partials).
// A=U (LDS, bf16, double-buffered, XOR-swizzled), B=X (direct L2 fragment
// loads, linear layout). D[n][b] transposed -> contiguous us4 epilogue stores.
template<bool CIN>
__global__ __launch_bounds__(256, 4) void k_gemm(
    const float* __restrict__ Ure, const float* __restrict__ Uim,
    const __hip_bfloat16* __restrict__ X, __hip_bfloat16* __restrict__ P)
{
  constexpr int NT = KCHUNK / BK;            // 8
  __shared__ __bf16 Us[2][2*BN*BK];          // 2 x 8 KB
  const int t = threadIdx.x;
  const int lane = t & 63, wid = t >> 6;
  const int n0 = blockIdx.x * BN;
  const int kb = blockIdx.y * KCHUNK;

  const f32x4 z4 = {0.f,0.f,0.f,0.f};
  f32x4 acc[2][2][2];                        // [mi][ni][re/im], D[n][b]
  #pragma unroll
  for (int mi = 0; mi < 2; ++mi)
    #pragma unroll
    for (int ni = 0; ni < 2; ++ni){ acc[mi][ni][0] = z4; acc[mi][ni][1] = z4; }

  // per-thread X base: row = wid*32 + mi*16 + (lane&15), k = kb + (lane>>4)*8
  const __hip_bfloat16* Xb = X + (size_t)(wid*32 + (lane & 15))*DIM + kb + ((lane >> 4) << 3);

  auto loadU = [&](int kk, float4 (&uv)[4]){
    #pragma unroll
    for (int r = 0; r < 4; ++r){
      const int idx = r*256 + t;             // 2c x 32rows x 16q
      const int c = idx >> 9, ci = idx & 511;
      const int row = ci >> 4, q = ci & 15;
      const float* us = c ? Uim : Ure;
      uv[r] = *reinterpret_cast<const float4*>(us + (size_t)(n0 + row)*DIM + kb + kk + q*4);
    }
  };
  auto writeU = [&](const float4 (&uv)[4], int bf){
    #pragma unroll
    for (int r = 0; r < 4; ++r){
      const int idx = r*256 + t;
      const int c = idx >> 9, ci = idx & 511;
      const int row = ci >> 4, q = ci & 15;
      union { __bf16 h[4]; unsigned long long u; } pk;
      pk.h[0]=(__bf16)uv[r].x; pk.h[1]=(__bf16)uv[r].y;
      pk.h[2]=(__bf16)uv[r].z; pk.h[3]=(__bf16)uv[r].w;
      const int e = (((q >> 1) ^ (row & 7)) << 3) | ((q & 1) << 2);
      *reinterpret_cast<unsigned long long*>(&Us[bf][c*BN*BK + row*BK + e]) = pk.u;
    }
  };

#define COMPUTE(TT, BF)                                                        \
  {                                                                            \
    _Pragma("unroll")                                                          \
    for (int ks = 0; ks < 2; ++ks){                                            \
      const int lc = ks*4 + (lane >> 4);                                       \
      bf16x8 ar[2], ai[2], br[2], bi[2];                                       \
      _Pragma("unroll")                                                        \
      for (int mi = 0; mi < 2; ++mi){                                          \
        const __hip_bfloat16* xp = Xb + (size_t)mi*16*DIM + (TT)*BK + ks*32;   \
        ar[mi] = *reinterpret_cast<const bf16x8*>(xp);                         \
        if (CIN) ai[mi] = *reinterpret_cast<const bf16x8*>(xp + BD);           \
      }                                                                        \
      _Pragma("unroll")                                                        \
      for (int ni = 0; ni < 2; ++ni){                                          \
        const int row = ni*16 + (lane & 15);                                   \
        const int off = row*BK + ((lc ^ (row & 7)) << 3);                      \
        br[ni] = *reinterpret_cast<const bf16x8*>(&Us[BF][off]);               \
        bi[ni] = *reinterpret_cast<const bf16x8*>(&Us[BF][BN*BK + off]);       \
      }                                                                        \
      _Pragma("unroll")                                                        \
      for (int mi = 0; mi < 2; ++mi){                                          \
        bf16x8 an = ar[mi];                                                    \
        if (CIN){                                                              \
          const u32x4 negu = __builtin_bit_cast(u32x4, ai[mi]) ^ 0x80008000u;  \
          an = __builtin_bit_cast(bf16x8, negu);                               \
        }                                                                      \
        _Pragma("unroll")                                                      \
        for (int ni = 0; ni < 2; ++ni){                                        \
          acc[mi][ni][0] = mfma16(br[ni], ar[mi], acc[mi][ni][0]);             \
          acc[mi][ni][1] = mfma16(bi[ni], ar[mi], acc[mi][ni][1]);             \
          if (CIN){                                                            \
            acc[mi][ni][0] = mfma16(bi[ni], an,     acc[mi][ni][0]);           \
            acc[mi][ni][1] = mfma16(br[ni], ai[mi], acc[mi][ni][1]);           \
          }                                                                    \
        }                                                                      \
      }                                                                        \
    }                                                                          \
  }

  float4 uvA[4], uvB[4];
  loadU(0, uvA);                             // prologue

#define GSTEP(TT, UC, UN, WAITS)                                               \
  {                                                                            \
    if ((TT) + 1 < NT) loadU(((TT)+1)*BK, UN);                                 \
    asm volatile("s_waitcnt vmcnt(" WAITS ")" ::: "memory");                   \
    __builtin_amdgcn_sched_barrier(0);                                         \
    writeU(UC, (TT) & 1);                                                      \
    asm volatile("s_waitcnt lgkmcnt(0)" ::: "memory");                         \
    __builtin_amdgcn_s_barrier();                                              \
    COMPUTE(TT, (TT) & 1);                                                     \
    __builtin_amdgcn_sched_barrier(0);                                         \
    __builtin_amdgcn_s_barrier();                                              \
  }

  GSTEP(0, uvA, uvB, "4")
  GSTEP(1, uvB, uvA, "4")
  GSTEP(2, uvA, uvB, "4")
  GSTEP(3, uvB, uvA, "4")
  GSTEP(4, uvA, uvB, "4")
  GSTEP(5, uvB, uvA, "4")
  GSTEP(6, uvA, uvB, "4")
  GSTEP(7, uvB, uvA, "0")
#undef GSTEP
#undef COMPUTE

  __hip_bfloat16* pre = P + (size_t)(blockIdx.y*2 + 0)*BD;
  __hip_bfloat16* pim = P + (size_t)(blockIdx.y*2 + 1)*BD;
  #pragma unroll
  for (int mi = 0; mi < 2; ++mi)
    #pragma unroll
    for (int ni = 0; ni < 2; ++ni){
      const int b  = wid*32 + mi*16 + (lane & 15);        // D col -> batch
      const int nb = n0 + ni*16 + (lane >> 4)*4;          // D rows -> 4 consecutive n
      union { __hip_bfloat16 h[4]; us4 v; } pk0, pk1;
      #pragma unroll
      for (int j = 0; j < 4; ++j){
        pk0.h[j] = __float2bfloat16(acc[mi][ni][0][j]);
        pk1.h[j] = __float2bfloat16(acc[mi][ni][1][j]);
      }
      *reinterpret_cast<us4*>(pre + (size_t)b*DIM + nb) = pk0.v;
      *reinterpret_cast<us4*>(pim + (size_t)b*DIM + nb) = pk1.v;
    }
}

// ------------------------------------------------- CNOT ring maps (GF(2)-linear)
__device__ __forceinline__ int cnot_inv(int x){   // inverse of forward dst-map
  #pragma unroll
  for (int i = 11; i >= 0; --i){
    const int cb = 11 - i;
    const int tb = 11 - ((i + 1) % 12);
    x ^= ((x >> cb) & 1) << tb;
  }
  return x;
}

// ----------------------------------- reduce + CNOT permute (gather, row in LDS)
// 2 blocks per batch row; each stages the full reduced row, writes half of it.
__global__ void k_perm(const __hip_bfloat16* __restrict__ P, __hip_bfloat16* __restrict__ dst){
  __shared__ float s[2][DIM];
  const int b = blockIdx.x >> 1, half = blockIdx.x & 1;
  const int t = threadIdx.x;                      // 512 threads
  #pragma unroll
  for (int h = 0; h < 2; ++h){
    const int idx = h*512 + t;                    // 0..1023 = 2c x 512 chunks
    const int c = idx >> 9, m0 = (idx & 511) * 8;
    float v[8];
    #pragma unroll
    for (int j = 0; j < 8; ++j) v[j] = 0.f;
    #pragma unroll
    for (int sp = 0; sp < KS; ++sp){
      const us8 vv = *reinterpret_cast<const us8*>(P + (size_t)(sp*2+c)*BD + (size_t)b*DIM + m0);
      #pragma unroll
      for (int j = 0; j < 8; ++j) v[j] += bf2f(vv[j]);
    }
    #pragma unroll
    for (int j = 0; j < 8; ++j) s[c][m0+j] = v[j];
  }
  __syncthreads();
  {
    const int c  = t >> 8;                        // 512 thr = 2c x 256 chunks
    const int k0 = half*2048 + (t & 255) * 8;
    union { __hip_bfloat16 e[8]; us8 v; } pk;
    #pragma unroll
    for (int j = 0; j < 8; ++j)
      pk.e[j] = __float2bfloat16(s[c][cnot_inv(k0 + j)]);
    *reinterpret_cast<us8*>(dst + (size_t)c*BD + (size_t)b*DIM + k0) = pk.v;
  }
}

// ----------------------------------------------- reduce + abs -> output f32
__global__ void k_abs(const __hip_bfloat16* __restrict__ P, float* __restrict__ dst){
  const int g = blockIdx.x * 256 + threadIdx.x;
  const int b = g >> 9;
  const int m0 = (g & 511) * 8;
  float re[8], im[8];
  #pragma unroll
  for (int j = 0; j < 8; ++j){ re[j] = 0.f; im[j] = 0.f; }
  #pragma unroll
  for (int sp = 0; sp < KS; ++sp){
    const us8 vr = *reinterpret_cast<const us8*>(P + (size_t)(sp*2+0)*BD + (size_t)b*DIM + m0);
    const us8 vi = *reinterpret_cast<const us8*>(P + (size_t)(sp*2+1)*BD + (size_t)b*DIM + m0);
    #pragma unroll
    for (int j = 0; j < 8; ++j){ re[j] += bf2f(vr[j]); im[j] += bf2f(vi[j]); }
  }
  #pragma unroll
  for (int j = 0; j < 8; ++j)
    dst[(size_t)b*DIM + m0 + j] = sqrtf(re[j]*re[j] + im[j]*im[j]);
}

// ---------------------------------------------------------------- QFT (1024 thr)
__global__ void k_qft(const __hip_bfloat16* __restrict__ P, __hip_bfloat16* __restrict__ out){
  __shared__ float sre[DIM];
  __shared__ float sim[DIM];
  const int b = blockIdx.x, t = threadIdx.x;      // 1024 threads
  {
    const int c  = t >> 9;                        // 0: re, 1: im
    const int m0 = (t & 511) * 8;
    float v[8];
    #pragma unroll
    for (int j = 0; j < 8; ++j) v[j] = 0.f;
    #pragma unroll
    for (int sp = 0; sp < KS; ++sp){
      const us8 vv = *reinterpret_cast<const us8*>(P + (size_t)(sp*2+c)*BD + (size_t)b*DIM + m0);
      #pragma unroll
      for (int j = 0; j < 8; ++j) v[j] += bf2f(vv[j]);
    }
    float* s0 = c ? sim : sre;
    #pragma unroll
    for (int j = 0; j < 8; ++j) s0[m0+j] = v[j];
  }
  __syncthreads();
  const float rs2 = 0.70710678118654752440f;
  const float pscale = 3.14159265358979323846f * 0x1p-32f;
  for (int m = 11; m >= 1; --m){
    const int p = 11 - m;
    const int mask = 1 << p;
    #pragma unroll
    for (int q = t; q < 2048; q += 1024){
      const int i0 = ((q & ~(mask-1)) << 1) | (q & (mask-1));
      const int i1 = i0 | mask;
      const float r0 = sre[i0], s0 = sim[i0], r1 = sre[i1], s1 = sim[i1];
      sre[i0] = (r0 + r1) * rs2; sim[i0] = (s0 + s1) * rs2;
      sre[i1] = (r0 - r1) * rs2; sim[i1] = (s0 - s1) * rs2;
    }
    __syncthreads();
    #pragma unroll
    for (int q = t; q < 2048; q += 1024){
      const int i1 = (((q & ~(mask-1)) << 1) | (q & (mask-1))) | mask;
      const unsigned u = (unsigned)(i1 >> (p + 1));
      const float phi = (float)__brev(u) * pscale;
      float cc, ss;
      __sincosf(phi, &ss, &cc);
      const float r = sre[i1], q2 = sim[i1];
      sre[i1] = r*cc - q2*ss;
      sim[i1] = r*ss + q2*cc;
    }
    __syncthreads();
  }
  {
    const int c  = t >> 9;
    const int i0 = (t & 511) * 8;
    const float* s0 = c ? sim : sre;
    union { __hip_bfloat16 e[8]; us8 s; } pk;
    #pragma unroll
    for (int j = 0; j < 8; ++j){
      const int rsrc = (int)(__brev((unsigned)(i0 + j)) >> 20);
      pk.e[j] = __float2bfloat16(s0[rsrc]);
    }
    *reinterpret_cast<us8*>(out + (size_t)c*BD + (size_t)b*DIM + i0) = pk.s;
  }
}

// ---------------------------------------------------------------- launch
extern "C" void kernel_launch(void* const* d_in, const int* in_sizes, int n_in,
                              void* d_out, int out_size, void* d_ws, size_t ws_size,
                              hipStream_t stream){
  const float* x   = (const float*)d_in[0];
  const float* Ure = (const float*)d_in[1];   // [4][DIM][DIM]
  const float* Uim = (const float*)d_in[2];
  float* out = (float*)d_out;

  __hip_bfloat16* P  = (__hip_bfloat16*)d_ws;          // 16.8 MB bf16 partials
  __hip_bfloat16* B0 = P + (size_t)KS*2*BD;            // 2 MB state
  __hip_bfloat16* B1 = B0 + (size_t)2*BD;              // 2 MB state
  const size_t UST = (size_t)DIM*DIM;
  const dim3 gg(DIM/BN, KS);                           // 128 x 8 = 1024 blocks

  k_normalize<<<BATCH, 256, 0, stream>>>(x, B0);
  // vqc(0): U0, CNOT ring, U1
  k_gemm<false><<<gg, 256, 0, stream>>>(Ure, Uim, B0, P);
  k_perm<<<2*BATCH, 512, 0, stream>>>(P, B1);
  k_gemm<true><<<gg, 256, 0, stream>>>(Ure + UST, Uim + UST, B1, P);
  // qft (consumes partials, writes B0)
  k_qft<<<BATCH, 1024, 0, stream>>>(P, B0);
  // vqc(1): U2, CNOT ring, U3
  k_gemm<true><<<gg, 256, 0, stream>>>(Ure + 2*UST, Uim + 2*UST, B0, P);
  k_perm<<<2*BATCH, 512, 0, stream>>>(P, B1);
  k_gemm<true><<<gg, 256, 0, stream>>>(Ure + 3*UST, Uim + 3*UST, B1, P);
  k_abs<<<BD/2048, 256, 0, stream>>>(P, out);
}

// Round 7
// 178.727 us; speedup vs baseline: 1.3061x; 1.3061x over previous
//
#include <hip/hip_runtime.h>
#include <hip/hip_bf16.h>
#include <math.h>

#define N_WIRES 12
#define DIM     4096
#define BATCH   128
#define BD      (BATCH*DIM)
#define BM      128
#define BN      32
#define BK      64
#define KS      4
#define KCHUNK  (DIM / KS)   // 1024

typedef __attribute__((ext_vector_type(4))) float f32x4;
typedef __attribute__((ext_vector_type(4))) unsigned int u32x4;
typedef __bf16 bf16x8 __attribute__((ext_vector_type(8)));
typedef __attribute__((ext_vector_type(8))) unsigned short us8;
typedef __attribute__((ext_vector_type(4))) unsigned short us4;

__device__ __forceinline__ f32x4 mfma16(bf16x8 a, bf16x8 b, f32x4 c){
  return __builtin_amdgcn_mfma_f32_16x16x32_bf16(a, b, c, 0, 0, 0);
}

__device__ __forceinline__ void gload16(const void* g, void* l){
  __builtin_amdgcn_global_load_lds(
    (const __attribute__((address_space(1))) unsigned int*)g,
    (__attribute__((address_space(3))) unsigned int*)l, 16, 0, 0);
}

__device__ __forceinline__ float bf2f(unsigned short u){
  union { unsigned int i; float f; } cv; cv.i = ((unsigned int)u) << 16; return cv.f;
}

// State layout (bf16): [c][b][DIM]; within each 64-col block the 16B chunks are
// XOR-swizzled by (b&7): elem j of row b at (j&~63) | ((((j>>3)&7)^(b&7))<<3) | (j&7).
// swz is an involution; chunk-aligned (low 3 bits identity).
__device__ __forceinline__ int swz(int j, int b){
  return (j & ~63) | (((((j >> 3) & 7) ^ (b & 7))) << 3) | (j & 7);
}

// ---------------------------------------------------------------- normalize
__global__ void k_normalize(const float* __restrict__ x, __hip_bfloat16* __restrict__ dst){
  const int b = blockIdx.x, t = threadIdx.x;
  const float4* xr = reinterpret_cast<const float4*>(x + (size_t)b * DIM);
  float4 v[4];
  float ss = 0.f;
  #pragma unroll
  for (int r = 0; r < 4; ++r){
    v[r] = xr[t*4 + r];
    ss += v[r].x*v[r].x + v[r].y*v[r].y + v[r].z*v[r].z + v[r].w*v[r].w;
  }
  #pragma unroll
  for (int off = 32; off > 0; off >>= 1) ss += __shfl_down(ss, off);
  __shared__ float sred[4];
  if ((t & 63) == 0) sred[t >> 6] = ss;
  __syncthreads();
  const float inv = 1.f / sqrtf(sred[0] + sred[1] + sred[2] + sred[3]);
  #pragma unroll
  for (int h = 0; h < 2; ++h){
    union { __bf16 e[8]; us8 s; } pk;
    const float* vv = reinterpret_cast<const float*>(&v[h*2]);
    #pragma unroll
    for (int j = 0; j < 8; ++j) pk.e[j] = (__bf16)(vv[j] * inv);
    const int j0 = t*16 + h*8;
    *reinterpret_cast<us8*>(dst + (size_t)b*DIM + swz(j0, b)) = pk.s;
  }
}

// ---------------------------------------------------------------- complex GEMM
// C[b,n] = sum_k U[n,k] * X[b,k], K split into KS partials (bf16 partials).
// A=U (reg-prefetch depth 4 -> LDS bf16 swizzled), B=X (gload_lds DMA, swizzled
// global layout). MFMA operands swapped (A=U frag) so D[n][b] -> contiguous
// us4 epilogue stores.
template<bool CIN>
__global__ __launch_bounds__(256, 2) void k_gemm(
    const float* __restrict__ Ure, const float* __restrict__ Uim,
    const __hip_bfloat16* __restrict__ X, __hip_bfloat16* __restrict__ P)
{
  constexpr int NCC = CIN ? 2 : 1;
  constexpr int NT  = KCHUNK / BK;           // 16
  __shared__ __bf16 Xs[2][NCC*BM*BK];        // 2 x 32 KB (16 KB real-only)
  __shared__ __bf16 Us[2][2*BN*BK];          // 2 x 8 KB
  const int t = threadIdx.x;
  const int lane = t & 63, wid = t >> 6;
  const int n0 = blockIdx.x * BN;
  const int kb = blockIdx.y * KCHUNK;

  const f32x4 z4 = {0.f,0.f,0.f,0.f};
  f32x4 acc[2][2][2];                        // [mi][ni][re/im], D[n][b]
  #pragma unroll
  for (int mi = 0; mi < 2; ++mi)
    #pragma unroll
    for (int ni = 0; ni < 2; ++ni){ acc[mi][ni][0] = z4; acc[mi][ni][1] = z4; }

  auto stageX = [&](int kk, int bf){
    #pragma unroll
    for (int r = 0; r < NCC*4; ++r){
      const int idx = r*256 + t;
      const int c = idx >> 10, ci = idx & 1023;
      const int row = ci >> 3, sc = ci & 7;
      gload16(X + (size_t)c*BD + (size_t)row*DIM + kb + kk + sc*8, &Xs[bf][idx*8]);
    }
  };
  auto loadU = [&](int kk, float4 (&uv)[4]){
    #pragma unroll
    for (int r = 0; r < 4; ++r){
      const int idx = r*256 + t;
      const int c = idx >> 9, ci = idx & 511;
      const int row = ci >> 4, q = ci & 15;
      const float* us = c ? Uim : Ure;
      uv[r] = *reinterpret_cast<const float4*>(us + (size_t)(n0 + row)*DIM + kb + kk + q*4);
    }
  };
  auto writeU = [&](const float4 (&uv)[4], int bf){
    #pragma unroll
    for (int r = 0; r < 4; ++r){
      const int idx = r*256 + t;
      const int c = idx >> 9, ci = idx & 511;
      const int row = ci >> 4, q = ci & 15;
      union { __bf16 h[4]; unsigned long long u; } pk;
      pk.h[0]=(__bf16)uv[r].x; pk.h[1]=(__bf16)uv[r].y;
      pk.h[2]=(__bf16)uv[r].z; pk.h[3]=(__bf16)uv[r].w;
      const int e = (((q >> 1) ^ (row & 7)) << 3) | ((q & 1) << 2);
      *reinterpret_cast<unsigned long long*>(&Us[bf][c*BN*BK + row*BK + e]) = pk.u;
    }
  };
  auto compute = [&](int bf){
    #pragma unroll
    for (int ks = 0; ks < 2; ++ks){
      const int lc = ks*4 + (lane >> 4);
      bf16x8 ar[2], ai[2], br[2], bi[2];
      #pragma unroll
      for (int mi = 0; mi < 2; ++mi){
        const int row = wid*32 + mi*16 + (lane & 15);
        const int off = row*BK + ((lc ^ (row & 7)) << 3);
        ar[mi] = *reinterpret_cast<const bf16x8*>(&Xs[bf][off]);
        if (CIN) ai[mi] = *reinterpret_cast<const bf16x8*>(&Xs[bf][BM*BK + off]);
      }
      #pragma unroll
      for (int ni = 0; ni < 2; ++ni){
        const int row = ni*16 + (lane & 15);
        const int off = row*BK + ((lc ^ (row & 7)) << 3);
        br[ni] = *reinterpret_cast<const bf16x8*>(&Us[bf][off]);
        bi[ni] = *reinterpret_cast<const bf16x8*>(&Us[bf][BN*BK + off]);
      }
      #pragma unroll
      for (int mi = 0; mi < 2; ++mi){
        bf16x8 an = ar[mi];
        if (CIN){
          const u32x4 negu = __builtin_bit_cast(u32x4, ai[mi]) ^ 0x80008000u;
          an = __builtin_bit_cast(bf16x8, negu);
        }
        #pragma unroll
        for (int ni = 0; ni < 2; ++ni){
          acc[mi][ni][0] = mfma16(br[ni], ar[mi], acc[mi][ni][0]);
          acc[mi][ni][1] = mfma16(bi[ni], ar[mi], acc[mi][ni][1]);
          if (CIN){
            acc[mi][ni][0] = mfma16(bi[ni], an,     acc[mi][ni][0]);
            acc[mi][ni][1] = mfma16(br[ni], ai[mi], acc[mi][ni][1]);
          }
        }
      }
    }
  };

  float4 uvA[4], uvB[4], uvC[4], uvD[4], uvE[4];
  // prologue: U0, X0, U1, U2, U3 (vmcnt counts at S0 are order-robust)
  loadU(0, uvA);
  stageX(0, 0);
  loadU(1*BK, uvB);
  loadU(2*BK, uvC);
  loadU(3*BK, uvD);

  // Step TT: stageX(TT+1), loadU(TT+4) [depth-4 issue -> 1KB sequential
  // outstanding per U row], counted FIFO wait, writeU(TT), barrier, compute.
#define GSTEP(TT, UC, UN, WAITS)                                               \
  {                                                                            \
    if ((TT) + 1 < NT) stageX(((TT)+1)*BK, ((TT)+1) & 1);                      \
    if ((TT) + 4 < NT) loadU(((TT)+4)*BK, UN);                                 \
    asm volatile("s_waitcnt vmcnt(" WAITS ")" ::: "memory");                   \
    __builtin_amdgcn_sched_barrier(0);                                         \
    writeU(UC, (TT) & 1);                                                      \
    asm volatile("s_waitcnt lgkmcnt(0)" ::: "memory");                         \
    __builtin_amdgcn_s_barrier();                                              \
    compute((TT) & 1);                                                         \
    __builtin_amdgcn_sched_barrier(0);                                         \
    __builtin_amdgcn_s_barrier();                                              \
  }

  GSTEP(0,  uvA, uvE, "12")
  GSTEP(1,  uvB, uvA, "16")
  GSTEP(2,  uvC, uvB, "16")
  GSTEP(3,  uvD, uvC, "16")
  GSTEP(4,  uvE, uvD, "16")
  GSTEP(5,  uvA, uvE, "16")
  GSTEP(6,  uvB, uvA, "16")
  GSTEP(7,  uvC, uvB, "16")
  GSTEP(8,  uvD, uvC, "16")
  GSTEP(9,  uvE, uvD, "16")
  GSTEP(10, uvA, uvE, "16")
  GSTEP(11, uvB, uvA, "16")
  GSTEP(12, uvC, uvB, "12")
  GSTEP(13, uvD, uvC, "8")
  GSTEP(14, uvE, uvD, "8")
  GSTEP(15, uvA, uvB, "0")
#undef GSTEP

  __hip_bfloat16* pre = P + (size_t)(blockIdx.y*2 + 0)*BD;
  __hip_bfloat16* pim = P + (size_t)(blockIdx.y*2 + 1)*BD;
  #pragma unroll
  for (int mi = 0; mi < 2; ++mi)
    #pragma unroll
    for (int ni = 0; ni < 2; ++ni){
      const int b  = wid*32 + mi*16 + (lane & 15);        // D col -> batch
      const int nb = n0 + ni*16 + (lane >> 4)*4;          // D rows -> 4 consecutive n
      union { __hip_bfloat16 h[4]; us4 v; } pk0, pk1;
      #pragma unroll
      for (int j = 0; j < 4; ++j){
        pk0.h[j] = __float2bfloat16(acc[mi][ni][0][j]);
        pk1.h[j] = __float2bfloat16(acc[mi][ni][1][j]);
      }
      *reinterpret_cast<us4*>(pre + (size_t)b*DIM + nb) = pk0.v;
      *reinterpret_cast<us4*>(pim + (size_t)b*DIM + nb) = pk1.v;
    }
}

// ------------------------------------------------- CNOT ring maps (GF(2)-linear)
__device__ __forceinline__ int cnot_inv(int x){   // inverse of forward dst-map
  #pragma unroll
  for (int i = 11; i >= 0; --i){
    const int cb = 11 - i;
    const int tb = 11 - ((i + 1) % 12);
    x ^= ((x >> cb) & 1) << tb;
  }
  return x;
}

// ----------------------------------- reduce + CNOT permute (gather, row in LDS)
// 2 blocks per batch row; each stages the full reduced row, writes half of it
// into the swizzled bf16 state layout.
__global__ void k_perm(const __hip_bfloat16* __restrict__ P, __hip_bfloat16* __restrict__ dst){
  __shared__ float s[2][DIM];
  const int b = blockIdx.x >> 1, half = blockIdx.x & 1;
  const int t = threadIdx.x;                      // 512 threads
  #pragma unroll
  for (int h = 0; h < 2; ++h){
    const int idx = h*512 + t;                    // 0..1023 = 2c x 512 chunks
    const int c = idx >> 9, m0 = (idx & 511) * 8;
    float v[8];
    #pragma unroll
    for (int j = 0; j < 8; ++j) v[j] = 0.f;
    #pragma unroll
    for (int sp = 0; sp < KS; ++sp){
      const us8 vv = *reinterpret_cast<const us8*>(P + (size_t)(sp*2+c)*BD + (size_t)b*DIM + m0);
      #pragma unroll
      for (int j = 0; j < 8; ++j) v[j] += bf2f(vv[j]);
    }
    #pragma unroll
    for (int j = 0; j < 8; ++j) s[c][m0+j] = v[j];
  }
  __syncthreads();
  {
    const int c  = t >> 8;                        // 512 thr = 2c x 256 chunks
    const int E0 = half*2048 + (t & 255) * 8;     // physical (swizzled) chunk
    const int k0 = swz(E0, b);                    // logical base (low3 = 0)
    union { __hip_bfloat16 e[8]; us8 v; } pk;
    #pragma unroll
    for (int j = 0; j < 8; ++j)
      pk.e[j] = __float2bfloat16(s[c][cnot_inv(k0 + j)]);
    *reinterpret_cast<us8*>(dst + (size_t)c*BD + (size_t)b*DIM + E0) = pk.v;
  }
}

// ----------------------------------------------- reduce + abs -> output f32
__global__ void k_abs(const __hip_bfloat16* __restrict__ P, float* __restrict__ dst){
  const int g = blockIdx.x * 256 + threadIdx.x;
  const int b = g >> 9;
  const int m0 = (g & 511) * 8;
  float re[8], im[8];
  #pragma unroll
  for (int j = 0; j < 8; ++j){ re[j] = 0.f; im[j] = 0.f; }
  #pragma unroll
  for (int sp = 0; sp < KS; ++sp){
    const us8 vr = *reinterpret_cast<const us8*>(P + (size_t)(sp*2+0)*BD + (size_t)b*DIM + m0);
    const us8 vi = *reinterpret_cast<const us8*>(P + (size_t)(sp*2+1)*BD + (size_t)b*DIM + m0);
    #pragma unroll
    for (int j = 0; j < 8; ++j){ re[j] += bf2f(vr[j]); im[j] += bf2f(vi[j]); }
  }
  #pragma unroll
  for (int j = 0; j < 8; ++j)
    dst[(size_t)b*DIM + m0 + j] = sqrtf(re[j]*re[j] + im[j]*im[j]);
}

// ---------------------------------------------------------------- QFT (1024 thr)
__global__ void k_qft(const __hip_bfloat16* __restrict__ P, __hip_bfloat16* __restrict__ out){
  __shared__ float sre[DIM];
  __shared__ float sim[DIM];
  const int b = blockIdx.x, t = threadIdx.x;      // 1024 threads
  {
    const int c  = t >> 9;                        // 0: re, 1: im
    const int m0 = (t & 511) * 8;
    float v[8];
    #pragma unroll
    for (int j = 0; j < 8; ++j) v[j] = 0.f;
    #pragma unroll
    for (int sp = 0; sp < KS; ++sp){
      const us8 vv = *reinterpret_cast<const us8*>(P + (size_t)(sp*2+c)*BD + (size_t)b*DIM + m0);
      #pragma unroll
      for (int j = 0; j < 8; ++j) v[j] += bf2f(vv[j]);
    }
    float* s0 = c ? sim : sre;
    #pragma unroll
    for (int j = 0; j < 8; ++j) s0[m0+j] = v[j];
  }
  __syncthreads();
  const float rs2 = 0.70710678118654752440f;
  const float pscale = 3.14159265358979323846f * 0x1p-32f;
  for (int m = 11; m >= 1; --m){
    const int p = 11 - m;
    const int mask = 1 << p;
    #pragma unroll
    for (int q = t; q < 2048; q += 1024){
      const int i0 = ((q & ~(mask-1)) << 1) | (q & (mask-1));
      const int i1 = i0 | mask;
      const float r0 = sre[i0], s0 = sim[i0], r1 = sre[i1], s1 = sim[i1];
      sre[i0] = (r0 + r1) * rs2; sim[i0] = (s0 + s1) * rs2;
      sre[i1] = (r0 - r1) * rs2; sim[i1] = (s0 - s1) * rs2;
    }
    __syncthreads();
    #pragma unroll
    for (int q = t; q < 2048; q += 1024){
      const int i1 = (((q & ~(mask-1)) << 1) | (q & (mask-1))) | mask;
      const unsigned u = (unsigned)(i1 >> (p + 1));
      const float phi = (float)__brev(u) * pscale;
      float cc, ss;
      __sincosf(phi, &ss, &cc);
      const float r = sre[i1], q2 = sim[i1];
      sre[i1] = r*cc - q2*ss;
      sim[i1] = r*ss + q2*cc;
    }
    __syncthreads();
  }
  {
    const int c  = t >> 9;
    const int E0 = (t & 511) * 8;                 // physical chunk
    const int i0 = swz(E0, b);                    // logical base
    const float* s0 = c ? sim : sre;
    union { __hip_bfloat16 e[8]; us8 s; } pk;
    #pragma unroll
    for (int j = 0; j < 8; ++j){
      const int rsrc = (int)(__brev((unsigned)(i0 + j)) >> 20);
      pk.e[j] = __float2bfloat16(s0[rsrc]);
    }
    *reinterpret_cast<us8*>(out + (size_t)c*BD + (size_t)b*DIM + E0) = pk.s;
  }
}

// ---------------------------------------------------------------- launch
extern "C" void kernel_launch(void* const* d_in, const int* in_sizes, int n_in,
                              void* d_out, int out_size, void* d_ws, size_t ws_size,
                              hipStream_t stream){
  const float* x   = (const float*)d_in[0];
  const float* Ure = (const float*)d_in[1];   // [4][DIM][DIM]
  const float* Uim = (const float*)d_in[2];
  float* out = (float*)d_out;

  __hip_bfloat16* P  = (__hip_bfloat16*)d_ws;          // 8.4 MB bf16 partials
  __hip_bfloat16* B0 = P + (size_t)KS*2*BD;            // 2 MB state
  __hip_bfloat16* B1 = B0 + (size_t)2*BD;              // 2 MB state
  const size_t UST = (size_t)DIM*DIM;
  const dim3 gg(DIM/BN, KS);                           // 128 x 4 = 512 blocks

  k_normalize<<<BATCH, 256, 0, stream>>>(x, B0);
  // vqc(0): U0, CNOT ring, U1
  k_gemm<false><<<gg, 256, 0, stream>>>(Ure, Uim, B0, P);
  k_perm<<<2*BATCH, 512, 0, stream>>>(P, B1);
  k_gemm<true><<<gg, 256, 0, stream>>>(Ure + UST, Uim + UST, B1, P);
  // qft (consumes partials, writes B0)
  k_qft<<<BATCH, 1024, 0, stream>>>(P, B0);
  // vqc(1): U2, CNOT ring, U3
  k_gemm<true><<<gg, 256, 0, stream>>>(Ure + 2*UST, Uim + 2*UST, B0, P);
  k_perm<<<2*BATCH, 512, 0, stream>>>(P, B1);
  k_gemm<true><<<gg, 256, 0, stream>>>(Ure + 3*UST, Uim + 3*UST, B1, P);
  k_abs<<<BD/2048, 256, 0, stream>>>(P, out);
}